// Round 11
// baseline (223.038 us; speedup 1.0000x reference)
//
#include <hip/hip_runtime.h>
#include <hip/hip_fp16.h>

#define N_NODES 50000
#define N_EDGES 800000
#define E2 (N_EDGES + N_NODES)   // 850000 edges incl self-loops

#define BSHIFT 6
#define BMASK 63
#define NBUCK 782            // ceil(50000/64) buckets of 64 dst each
#define GRPS 8
#define SUBCAP 256           // per (bucket,group) record capacity
#define BUCKCAP (GRPS * SUBCAP)
#define CURPAD 32            // ints per cursor (128B line padding)

typedef _Float16 h8v __attribute__((ext_vector_type(8)));
typedef float f4v __attribute__((ext_vector_type(4)));

// physical XCD id (gfx950: HW_REG_XCC_ID = hwreg 20, bits [3:0])
__device__ __forceinline__ int xcc_id() {
    return (int)__builtin_amdgcn_s_getreg(20 | (0 << 6) | ((4 - 1) << 11)) & (GRPS - 1);
}

// ---------------- CSR build: XCD-pure grouped scatter ----------------

__global__ __launch_bounds__(256) void k_gscatter(const int* __restrict__ ei,
        int* __restrict__ bcur, unsigned int* __restrict__ brec,
        int* __restrict__ ocnt, unsigned int* __restrict__ obuf) {
    int e = blockIdx.x * 256 + threadIdx.x;
    if (e >= E2) return;
    int src, dst;
    if (e < N_EDGES) { src = ei[e]; dst = ei[N_EDGES + e]; }
    else             { src = dst = e - N_EDGES; }
    int b = dst >> BSHIFT;
    int g = xcc_id();      // XCD-pure: one L2 owns each sub-region's lines
    int pos = atomicAdd(&bcur[(b * GRPS + g) * CURPAD], 1);
    if (pos < SUBCAP) {
        brec[b * BUCKCAP + g * SUBCAP + pos] =
            ((unsigned int)(dst & BMASK) << 16) | (unsigned int)src;
    } else {
        int op = atomicAdd(ocnt, 1);       // fallback, normally never taken
        obuf[op] = ((unsigned int)dst << 16) | (unsigned int)src;
    }
}

// 1 block: bucket totals (cursors + overflow) -> exclusive scan -> boff; + W2 pad
__global__ __launch_bounds__(1024) void k_segscan(const int* __restrict__ bcur,
        int* __restrict__ boff, const float* __restrict__ W2, float* __restrict__ W2p,
        const int* __restrict__ ocnt, const unsigned int* __restrict__ obuf) {
    int t = threadIdx.x;
    for (int i = t; i < 128 * 48; i += 1024) {
        int k = i / 48, c = i - k * 48;
        W2p[i] = (c < 47) ? W2[k * 47 + c] : 0.f;
    }
    __shared__ int ovh[NBUCK];
    for (int i = t; i < NBUCK; i += 1024) ovh[i] = 0;
    __syncthreads();
    int oc = *ocnt;
    for (int i = t; i < oc; i += 1024)
        atomicAdd(&ovh[(obuf[i] >> 16) >> BSHIFT], 1);
    __syncthreads();
    int v = 0;
    if (t < NBUCK) {
        #pragma unroll
        for (int g = 0; g < GRPS; ++g) {
            int c = bcur[(t * GRPS + g) * CURPAD];
            v += (c < SUBCAP) ? c : SUBCAP;
        }
        v += ovh[t];
    }
    __shared__ int ws[16];
    int lane = t & 63, w = t >> 6;
    int x = v;
    #pragma unroll
    for (int o = 1; o < 64; o <<= 1) { int y = __shfl_up(x, o); if (lane >= o) x += y; }
    if (lane == 63) ws[w] = x;
    __syncthreads();
    if (t == 0) {
        #pragma unroll
        for (int j = 1; j < 16; ++j) ws[j] += ws[j - 1];
    }
    __syncthreads();
    int add = (w == 0) ? 0 : ws[w - 1];
    int excl = add + x - v;
    if (t < NBUCK) boff[t] = excl;
    if (t == NBUCK - 1) boff[NBUCK] = excl + v;
}

// per-bucket finalize: LDS histogram/scan/scatter -> coalesced csr write + offs
__global__ __launch_bounds__(256) void k_finalize(const unsigned int* __restrict__ brec,
        const int* __restrict__ bcur, const int* __restrict__ boff,
        unsigned short* __restrict__ csr_src, int* __restrict__ offs,
        const int* __restrict__ ocnt, const unsigned int* __restrict__ obuf) {
    int B = blockIdx.x;
    int tid = threadIdx.x;
    __shared__ int hist[64], cur[64], cnt_s[GRPS];
    __shared__ unsigned short stage[BUCKCAP];
    if (tid < 64) hist[tid] = 0;
    if (tid < GRPS) {
        int c = bcur[(B * GRPS + tid) * CURPAD];
        cnt_s[tid] = (c < SUBCAP) ? c : SUBCAP;
    }
    __syncthreads();
    const unsigned int* bp = brec + (size_t)B * BUCKCAP;
    #pragma unroll
    for (int g = 0; g < GRPS; ++g) {
        int c = cnt_s[g];
        for (int i = tid; i < c; i += 256) atomicAdd(&hist[bp[g * SUBCAP + i] >> 16], 1);
    }
    int oc = *ocnt;
    if (oc > 0) {
        for (int i = tid; i < oc; i += 256) {
            unsigned int r = obuf[i];
            if ((int)((r >> 16) >> BSHIFT) == B) atomicAdd(&hist[(r >> 16) & BMASK], 1);
        }
    }
    __syncthreads();
    int base = boff[B];
    int total = boff[B + 1] - base;
    if (tid < 64) {   // wave 0: exclusive scan over 64 node-counts
        int v = hist[tid];
        int x = v;
        #pragma unroll
        for (int o = 1; o < 64; o <<= 1) { int y = __shfl_up(x, o); if (tid >= o) x += y; }
        int excl = x - v;
        cur[tid] = excl;
        int n = B * 64 + tid;
        if (n < N_NODES) offs[n] = base + excl;
    }
    if (B == NBUCK - 1 && tid == 0) offs[N_NODES] = boff[NBUCK];
    __syncthreads();
    if (total <= BUCKCAP) {
        #pragma unroll
        for (int g = 0; g < GRPS; ++g) {
            int c = cnt_s[g];
            for (int i = tid; i < c; i += 256) {
                unsigned int r = bp[g * SUBCAP + i];
                int p = atomicAdd(&cur[r >> 16], 1);
                stage[p] = (unsigned short)(r & 0xFFFFu);
            }
        }
        if (oc > 0) {
            for (int i = tid; i < oc; i += 256) {
                unsigned int r = obuf[i];
                if ((int)((r >> 16) >> BSHIFT) == B) {
                    int p = atomicAdd(&cur[(r >> 16) & BMASK], 1);
                    stage[p] = (unsigned short)(r & 0xFFFFu);
                }
            }
        }
        __syncthreads();
        for (int i = tid; i < total; i += 256) csr_src[base + i] = stage[i];
    } else {   // fallback: direct (uncoalesced) writes
        #pragma unroll
        for (int g = 0; g < GRPS; ++g) {
            int c = cnt_s[g];
            for (int i = tid; i < c; i += 256) {
                unsigned int r = bp[g * SUBCAP + i];
                int p = atomicAdd(&cur[r >> 16], 1);
                csr_src[base + p] = (unsigned short)(r & 0xFFFFu);
            }
        }
        if (oc > 0) {
            for (int i = tid; i < oc; i += 256) {
                unsigned int r = obuf[i];
                if ((int)((r >> 16) >> BSHIFT) == B) {
                    int p = atomicAdd(&cur[(r >> 16) & BMASK], 1);
                    csr_src[base + p] = (unsigned short)(r & 0xFFFFu);
                }
            }
        }
    }
}

// ------- W1 transpose+fp16: W1T[c][k] = W1[k][c] -------

__global__ void k_prepw1(const float* __restrict__ W1, _Float16* __restrict__ W1T) {
    int i = blockIdx.x * 256 + threadIdx.x;   // 128*256
    if (i >= 128 * 256) return;
    int c = i >> 8, k = i & 255;
    W1T[i] = (_Float16)W1[k * 128 + c];
}

// ------- GEMM1 (MFMA): h1h = fp16(x @ W1), no LDS -------

__global__ __launch_bounds__(128) void k_gemm1(const float* __restrict__ x,
        const _Float16* __restrict__ W1T, _Float16* __restrict__ h1h) {
    int lane = threadIdx.x & 63;
    int wv = threadIdx.x >> 6;            // 0..1
    int rowbase = blockIdx.x * 64 + wv * 32;
    int r0 = lane & 15;
    int kg = lane >> 4;                   // 0..3
    f4v acc[2][8];
    #pragma unroll
    for (int i = 0; i < 2; ++i)
        #pragma unroll
        for (int j = 0; j < 8; ++j) acc[i][j] = (f4v)0.f;

    #pragma unroll 1
    for (int kt = 0; kt < 256; kt += 32) {
        h8v a[2];
        #pragma unroll
        for (int rf = 0; rf < 2; ++rf) {
            int row = rowbase + rf * 16 + r0;
            if (row >= N_NODES) row = N_NODES - 1;
            const float* ap = x + (size_t)row * 256 + kt + kg * 8;
            float4 lo = *(const float4*)ap;
            float4 hi = *(const float4*)(ap + 4);
            h8v t;
            t[0] = (_Float16)lo.x; t[1] = (_Float16)lo.y;
            t[2] = (_Float16)lo.z; t[3] = (_Float16)lo.w;
            t[4] = (_Float16)hi.x; t[5] = (_Float16)hi.y;
            t[6] = (_Float16)hi.z; t[7] = (_Float16)hi.w;
            a[rf] = t;
        }
        #pragma unroll
        for (int cf = 0; cf < 8; ++cf) {
            h8v b = *(const h8v*)(W1T + (size_t)(cf * 16 + r0) * 256 + kt + kg * 8);
            acc[0][cf] = __builtin_amdgcn_mfma_f32_16x16x32_f16(a[0], b, acc[0][cf], 0, 0, 0);
            acc[1][cf] = __builtin_amdgcn_mfma_f32_16x16x32_f16(a[1], b, acc[1][cf], 0, 0, 0);
        }
    }
    // C/D: col = lane&15, row = (lane>>4)*4 + reg
    #pragma unroll
    for (int rf = 0; rf < 2; ++rf) {
        #pragma unroll
        for (int r = 0; r < 4; ++r) {
            int row = rowbase + rf * 16 + kg * 4 + r;
            if (row < N_NODES) {
                _Float16* orow = h1h + (size_t)row * 128 + r0;
                #pragma unroll
                for (int cf = 0; cf < 8; ++cf)
                    orow[cf * 16] = (_Float16)acc[rf][cf][r];
            }
        }
    }
}

// ------- per-node attention logits, layer 1 (reads fp16 h1) -------

__global__ void k_logits1(const __half* __restrict__ h1h,
                          const float* __restrict__ a1s, const float* __restrict__ a1d,
                          float* __restrict__ s1s, float* __restrict__ s1d) {
    int idx = blockIdx.x * blockDim.x + threadIdx.x;   // N*8
    if (idx >= N_NODES * 8) return;
    int n = idx >> 3, h = idx & 7;
    const __half2* hp2 = (const __half2*)(h1h + (size_t)n * 128 + h * 16);
    float ss = 0.f, sd = 0.f;
    #pragma unroll
    for (int c2 = 0; c2 < 8; ++c2) {
        float2 v = __half22float2(hp2[c2]);
        ss += v.x * a1s[h * 16 + 2 * c2] + v.y * a1s[h * 16 + 2 * c2 + 1];
        sd += v.x * a1d[h * 16 + 2 * c2] + v.y * a1d[h * 16 + 2 * c2 + 1];
    }
    s1s[idx] = ss;
    s1d[idx] = sd;
}

// ------- layer-1 aggregate + bias + ELU (wave per node, single fused pass) -------

__global__ __launch_bounds__(256) void k_agg1(const __half* __restrict__ h1h,
        const float* __restrict__ s1s, const float* __restrict__ s1d,
        const int* __restrict__ offs, const unsigned short* __restrict__ csr_src,
        const float* __restrict__ b1, float* __restrict__ h2o) {
    int wave = threadIdx.x >> 6;
    int lane = threadIdx.x & 63;
    int n = blockIdx.x * 4 + wave;   // N = 4*12500 exactly
    int beg = offs[n];
    int deg = offs[n + 1] - beg;     // >= 1 (self-loop)

    int h = lane & 7;        // head this lane evaluates exp for
    int slot = lane >> 3;    // edge slot within 8-chunk
    int hd = lane >> 3;      // head of this lane's channel pair
    float sdh = s1d[n * 8 + h];

    float dsum = 0.f;
    float accx = 0.f, accy = 0.f;
    for (int chunk = 0; chunk < deg; chunk += 8) {
        int i = chunk + slot;
        int esrc = csr_src[beg + ((i < deg) ? i : (deg - 1))];   // clamped, valid
        float aN = 0.f;
        if (i < deg) {
            float e = s1s[esrc * 8 + h] + sdh;
            e = (e > 0.f) ? e : 0.2f * e;
            aN = __expf(e);          // no max subtraction needed
            dsum += aN;
        }
        int   srcs[8];
        float as[8];
        #pragma unroll
        for (int s = 0; s < 8; ++s) {
            srcs[s] = __shfl(esrc, s * 8);
            as[s]   = __shfl(aN, s * 8 + hd);   // 0 for inactive slots
        }
        __half2 v[8];
        #pragma unroll
        for (int s = 0; s < 8; ++s)
            v[s] = *(const __half2*)(h1h + (size_t)srcs[s] * 128 + 2 * lane);
        #pragma unroll
        for (int s = 0; s < 8; ++s) {
            float2 vf = __half22float2(v[s]);
            accx += as[s] * vf.x;
            accy += as[s] * vf.y;
        }
    }
    dsum += __shfl_xor(dsum, 8);
    dsum += __shfl_xor(dsum, 16);
    dsum += __shfl_xor(dsum, 32);
    float rd = 1.f / __shfl(dsum, hd);

    float v0 = accx * rd + b1[2 * lane];
    v0 = (v0 > 0.f) ? v0 : (__expf(v0) - 1.f);
    float v1 = accy * rd + b1[2 * lane + 1];
    v1 = (v1 > 0.f) ? v1 : (__expf(v1) - 1.f);
    *(float2*)(h2o + (size_t)n * 128 + 2 * lane) = make_float2(v0, v1);
}

// ------- GEMM2: g2h(fp16) = h2 @ W2  (thread = node, 48 accs) + logits -------

__global__ __launch_bounds__(256) void k_gemm2(const float* __restrict__ h2,
        const float* __restrict__ W2p,
        const float* __restrict__ a2s, const float* __restrict__ a2d,
        __half* __restrict__ g2h, float* __restrict__ s2s, float* __restrict__ s2d) {
    int n = blockIdx.x * 256 + threadIdx.x;
    bool valid = (n < N_NODES);
    int nn = valid ? n : (N_NODES - 1);
    const float* hrow = h2 + (size_t)nn * 128;
    float4 acc[12];
    #pragma unroll
    for (int j = 0; j < 12; ++j) acc[j] = make_float4(0.f, 0.f, 0.f, 0.f);
    #pragma unroll 1
    for (int k = 0; k < 128; k += 4) {
        float4 hv = *(const float4*)(hrow + k);
        float hk[4] = {hv.x, hv.y, hv.z, hv.w};
        #pragma unroll
        for (int kk = 0; kk < 4; ++kk) {
            const float* wrow = W2p + (size_t)(k + kk) * 48;
            #pragma unroll
            for (int j = 0; j < 12; ++j) {
                float4 wv = *(const float4*)(wrow + j * 4);
                acc[j].x += hk[kk] * wv.x;
                acc[j].y += hk[kk] * wv.y;
                acc[j].z += hk[kk] * wv.z;
                acc[j].w += hk[kk] * wv.w;
            }
        }
    }
    float vs = 0.f, vd = 0.f;
    #pragma unroll
    for (int j = 0; j < 12; ++j) {
        int c = j * 4;
        vs += acc[j].x * a2s[c + 0]; vd += acc[j].x * a2d[c + 0];
        vs += acc[j].y * a2s[c + 1]; vd += acc[j].y * a2d[c + 1];
        vs += acc[j].z * a2s[c + 2]; vd += acc[j].z * a2d[c + 2];
        if (j < 11) { vs += acc[j].w * a2s[c + 3]; vd += acc[j].w * a2d[c + 3]; }
    }
    if (valid) {
        __half2* orow = (__half2*)(g2h + (size_t)n * 48);
        #pragma unroll
        for (int j = 0; j < 12; ++j) {
            orow[j * 2 + 0] = __floats2half2_rn(acc[j].x, acc[j].y);
            orow[j * 2 + 1] = __floats2half2_rn(acc[j].z, acc[j].w);
        }
        s2s[n] = vs;
        s2d[n] = vd;
    }
}

// ------- layer-2 aggregate + bias + log_softmax (single fused pass) -------

__global__ __launch_bounds__(256) void k_agg2(const __half* __restrict__ g2h,
        const float* __restrict__ s2s, const float* __restrict__ s2d,
        const int* __restrict__ offs, const unsigned short* __restrict__ csr_src,
        const float* __restrict__ b2, float* __restrict__ outp) {
    int wave = threadIdx.x >> 6, lane = threadIdx.x & 63;
    int n = blockIdx.x * 4 + wave;
    int beg = offs[n];
    int deg = offs[n + 1] - beg;
    float sdn = s2d[n];
    int c = (lane < 47) ? lane : 47;   // col 47 is zero padding, valid address

    float dsum = 0.f;
    float acc = 0.f;
    for (int chunk = 0; chunk < deg; chunk += 64) {
        int i = chunk + lane;
        int esrc = csr_src[beg + ((i < deg) ? i : (deg - 1))];
        float aN = 0.f;
        if (i < deg) {
            float e = s2s[esrc] + sdn;
            e = (e > 0.f) ? e : 0.2f * e;
            aN = __expf(e);
            dsum += aN;
        }
        int lim = deg - chunk; if (lim > 64) lim = 64;
        for (int g = 0; g < lim; g += 8) {
            int   srcs[8];
            float as[8];
            #pragma unroll
            for (int s = 0; s < 8; ++s) {
                srcs[s] = __shfl(esrc, g + s);
                as[s]   = __shfl(aN, g + s);     // 0 for inactive
            }
            __half v[8];
            #pragma unroll
            for (int s = 0; s < 8; ++s) v[s] = g2h[(size_t)srcs[s] * 48 + c];
            #pragma unroll
            for (int s = 0; s < 8; ++s) acc += as[s] * __half2float(v[s]);
        }
    }
    #pragma unroll
    for (int o = 32; o; o >>= 1) dsum += __shfl_xor(dsum, o);
    acc *= 1.f / dsum;

    float l = (lane < 47) ? acc + b2[lane] : -1e30f;
    float rm = l;
    #pragma unroll
    for (int o = 32; o; o >>= 1) rm = fmaxf(rm, __shfl_xor(rm, o));
    float p = (lane < 47) ? __expf(l - rm) : 0.f;
    float ps = p;
    #pragma unroll
    for (int o = 32; o; o >>= 1) ps += __shfl_xor(ps, o);
    float lse = rm + __logf(ps);
    if (lane < 47) outp[(size_t)n * 47 + lane] = l - lse;
}

// ---------------- launcher ----------------

extern "C" void kernel_launch(void* const* d_in, const int* in_sizes, int n_in,
                              void* d_out, int out_size, void* d_ws, size_t ws_size,
                              hipStream_t stream) {
    const float* x   = (const float*)d_in[0];
    const int*   ei  = (const int*)d_in[1];
    const float* W1  = (const float*)d_in[2];
    const float* a1s = (const float*)d_in[3];
    const float* a1d = (const float*)d_in[4];
    const float* b1  = (const float*)d_in[5];
    const float* W2  = (const float*)d_in[6];
    const float* a2s = (const float*)d_in[7];
    const float* a2d = (const float*)d_in[8];
    const float* b2  = (const float*)d_in[9];
    float* outp = (float*)d_out;

    char* ws = (char*)d_ws;
    size_t off = 0;
    auto alloc = [&](size_t bytes) -> void* {
        void* p = ws + off;
        off += (bytes + 255) & ~(size_t)255;
        return p;
    };
    int* bcur    = (int*)alloc((size_t)NBUCK * GRPS * CURPAD * 4);
    int* boff    = (int*)alloc((size_t)(NBUCK + 1) * 4);
    unsigned int* brec = (unsigned int*)alloc((size_t)NBUCK * BUCKCAP * 4);
    unsigned short* csr_src = (unsigned short*)alloc((size_t)E2 * 2);
    int* offs    = (int*)alloc((size_t)(N_NODES + 1) * 4);
    int* ocnt    = (int*)alloc(256);
    unsigned int* obuf = (unsigned int*)alloc((size_t)E2 * 4);
    __half* h1h  = (__half*)alloc((size_t)N_NODES * 128 * 2);
    float* s1s   = (float*)alloc((size_t)N_NODES * 8 * 4);
    float* s1d   = (float*)alloc((size_t)N_NODES * 8 * 4);
    float* h2    = (float*)alloc((size_t)N_NODES * 128 * 4);
    __half* g2h  = (__half*)alloc((size_t)N_NODES * 48 * 2);
    float* s2s   = (float*)alloc((size_t)N_NODES * 4);
    float* s2d   = (float*)alloc((size_t)N_NODES * 4);
    float* W2p   = (float*)alloc((size_t)128 * 48 * 4);
    _Float16* W1T = (_Float16*)alloc((size_t)128 * 256 * 2);

    (void)in_sizes; (void)n_in; (void)out_size; (void)ws_size;

    // CSR build + weight prep
    hipMemsetAsync(bcur, 0, (size_t)NBUCK * GRPS * CURPAD * 4, stream);
    hipMemsetAsync(ocnt, 0, 4, stream);
    k_prepw1<<<128, 256, 0, stream>>>(W1, W1T);
    k_gscatter<<<(E2 + 255) / 256, 256, 0, stream>>>(ei, bcur, brec, ocnt, obuf);
    k_segscan<<<1, 1024, 0, stream>>>(bcur, boff, W2, W2p, ocnt, obuf);
    k_finalize<<<NBUCK, 256, 0, stream>>>(brec, bcur, boff, csr_src, offs, ocnt, obuf);

    // layer 1
    k_gemm1<<<(N_NODES + 63) / 64, 128, 0, stream>>>(x, W1T, (_Float16*)h1h);
    k_logits1<<<(N_NODES * 8 + 255) / 256, 256, 0, stream>>>(h1h, a1s, a1d, s1s, s1d);
    k_agg1<<<N_NODES / 4, 256, 0, stream>>>(h1h, s1s, s1d, offs, csr_src, b1, h2);

    // layer 2
    k_gemm2<<<(N_NODES + 255) / 256, 256, 0, stream>>>(h2, W2p, a2s, a2d, g2h, s2s, s2d);
    k_agg2<<<N_NODES / 4, 256, 0, stream>>>(g2h, s2s, s2d, offs, csr_src, b2, outp);
}

// Round 12
// 181.462 us; speedup vs baseline: 1.2291x; 1.2291x over previous
//
#include <hip/hip_runtime.h>
#include <hip/hip_fp16.h>

#define N_NODES 50000
#define N_EDGES 800000
#define E2 (N_EDGES + N_NODES)   // 850000 edges incl self-loops

#define BSHIFT 6
#define BMASK 63
#define NBUCK 782            // ceil(50000/64) buckets of 64 dst each
#define EPB 4096             // edges per block in counting sort
#define NBLKC 208            // ceil(E2/EPB)

typedef _Float16 h8v __attribute__((ext_vector_type(8)));
typedef float f4v __attribute__((ext_vector_type(4)));

// ---------------- CSR build: counting sort (no global atomics) ----------------

// phase A: per-block LDS histogram -> gh[blk][b]
__global__ __launch_bounds__(256) void k_hist(const int* __restrict__ ei,
                                              int* __restrict__ gh) {
    __shared__ int h[NBUCK];
    int tid = threadIdx.x;
    for (int b = tid; b < NBUCK; b += 256) h[b] = 0;
    __syncthreads();
    int base = blockIdx.x * EPB;
    for (int i = tid; i < EPB; i += 256) {
        int e = base + i;
        if (e < E2) {
            int dst = (e < N_EDGES) ? ei[N_EDGES + e] : (e - N_EDGES);
            atomicAdd(&h[dst >> BSHIFT], 1);
        }
    }
    __syncthreads();
    for (int b = tid; b < NBUCK; b += 256) gh[blockIdx.x * NBUCK + b] = h[b];
}

// phase B1: per-bucket exclusive scan across blocks (wave per bucket)
__global__ __launch_bounds__(256) void k_colscan(int* __restrict__ gh,
                                                 int* __restrict__ tot) {
    int wave = threadIdx.x >> 6, lane = threadIdx.x & 63;
    int b = blockIdx.x * 4 + wave;
    if (b >= NBUCK) return;
    int carry = 0;
    for (int c = 0; c < NBLKC; c += 64) {
        int k = c + lane;
        int v = (k < NBLKC) ? gh[k * NBUCK + b] : 0;
        int x = v;
        #pragma unroll
        for (int o = 1; o < 64; o <<= 1) { int y = __shfl_up(x, o); if (lane >= o) x += y; }
        if (k < NBLKC) gh[k * NBUCK + b] = carry + x - v;   // exclusive
        carry += __shfl(x, 63);
    }
    if (lane == 0) tot[b] = carry;
}

// phase B2 (1 block): scan bucket totals -> boff; + W2 pad
__global__ __launch_bounds__(1024) void k_btot(const int* __restrict__ tot,
        int* __restrict__ boff, const float* __restrict__ W2, float* __restrict__ W2p) {
    int t = threadIdx.x;
    for (int i = t; i < 128 * 48; i += 1024) {
        int k = i / 48, c = i - k * 48;
        W2p[i] = (c < 47) ? W2[k * 47 + c] : 0.f;
    }
    int v = (t < NBUCK) ? tot[t] : 0;
    __shared__ int ws[16];
    int lane = t & 63, w = t >> 6;
    int x = v;
    #pragma unroll
    for (int o = 1; o < 64; o <<= 1) { int y = __shfl_up(x, o); if (lane >= o) x += y; }
    if (lane == 63) ws[w] = x;
    __syncthreads();
    if (t == 0) {
        #pragma unroll
        for (int j = 1; j < 16; ++j) ws[j] += ws[j - 1];
    }
    __syncthreads();
    int add = (w == 0) ? 0 : ws[w - 1];
    int excl = add + x - v;
    if (t < NBUCK) boff[t] = excl;
    if (t == NBUCK - 1) boff[NBUCK] = excl + v;
}

// phase C: deterministic placement (LDS ranks only)
__global__ __launch_bounds__(256) void k_place(const int* __restrict__ ei,
        const int* __restrict__ gh, const int* __restrict__ boff,
        unsigned int* __restrict__ brec) {
    __shared__ int sbase[NBUCK];
    __shared__ int cnt[NBUCK];
    int tid = threadIdx.x;
    for (int b = tid; b < NBUCK; b += 256) {
        sbase[b] = boff[b] + gh[blockIdx.x * NBUCK + b];
        cnt[b] = 0;
    }
    __syncthreads();
    int base = blockIdx.x * EPB;
    for (int i = tid; i < EPB; i += 256) {
        int e = base + i;
        if (e < E2) {
            int src, dst;
            if (e < N_EDGES) { src = ei[e]; dst = ei[N_EDGES + e]; }
            else             { src = dst = e - N_EDGES; }
            int b = dst >> BSHIFT;
            int r = atomicAdd(&cnt[b], 1);
            brec[sbase[b] + r] = ((unsigned int)(dst & BMASK) << 16) | (unsigned int)src;
        }
    }
}

// per-bucket finalize: LDS histogram/scan/scatter -> coalesced csr write + offs
__global__ __launch_bounds__(256) void k_finalize(const unsigned int* __restrict__ brec,
        const int* __restrict__ boff, unsigned short* __restrict__ csr_src,
        int* __restrict__ offs) {
    int B = blockIdx.x;
    int tid = threadIdx.x;
    int base = boff[B];
    int total = boff[B + 1] - base;
    __shared__ int hist[64], cur[64];
    __shared__ unsigned short stage[2048];
    if (tid < 64) hist[tid] = 0;
    __syncthreads();
    const unsigned int* bp = brec + base;
    for (int i = tid; i < total; i += 256) atomicAdd(&hist[bp[i] >> 16], 1);
    __syncthreads();
    if (tid < 64) {   // wave 0: exclusive scan over 64 node-counts
        int v = hist[tid];
        int x = v;
        #pragma unroll
        for (int o = 1; o < 64; o <<= 1) { int y = __shfl_up(x, o); if (tid >= o) x += y; }
        int excl = x - v;
        cur[tid] = excl;
        int n = B * 64 + tid;
        if (n < N_NODES) offs[n] = base + excl;
    }
    if (B == NBUCK - 1 && tid == 0) offs[N_NODES] = boff[NBUCK];
    __syncthreads();
    if (total <= 2048) {
        for (int i = tid; i < total; i += 256) {
            unsigned int r = bp[i];
            int p = atomicAdd(&cur[r >> 16], 1);
            stage[p] = (unsigned short)(r & 0xFFFFu);
        }
        __syncthreads();
        for (int i = tid; i < total; i += 256) csr_src[base + i] = stage[i];
    } else {   // safety fallback (never hit for this graph)
        for (int i = tid; i < total; i += 256) {
            unsigned int r = bp[i];
            int p = atomicAdd(&cur[r >> 16], 1);
            csr_src[base + p] = (unsigned short)(r & 0xFFFFu);
        }
    }
}

// ------- W1 transpose+fp16: W1T[c][k] = W1[k][c] -------

__global__ void k_prepw1(const float* __restrict__ W1, _Float16* __restrict__ W1T) {
    int i = blockIdx.x * 256 + threadIdx.x;   // 128*256
    if (i >= 128 * 256) return;
    int c = i >> 8, k = i & 255;
    W1T[i] = (_Float16)W1[k * 128 + c];
}

// ------- GEMM1 (MFMA): h1h = fp16(x @ W1), no LDS -------

__global__ __launch_bounds__(128) void k_gemm1(const float* __restrict__ x,
        const _Float16* __restrict__ W1T, _Float16* __restrict__ h1h) {
    int lane = threadIdx.x & 63;
    int wv = threadIdx.x >> 6;            // 0..1
    int rowbase = blockIdx.x * 64 + wv * 32;
    int r0 = lane & 15;
    int kg = lane >> 4;                   // 0..3
    f4v acc[2][8];
    #pragma unroll
    for (int i = 0; i < 2; ++i)
        #pragma unroll
        for (int j = 0; j < 8; ++j) acc[i][j] = (f4v)0.f;

    #pragma unroll 1
    for (int kt = 0; kt < 256; kt += 32) {
        h8v a[2];
        #pragma unroll
        for (int rf = 0; rf < 2; ++rf) {
            int row = rowbase + rf * 16 + r0;
            if (row >= N_NODES) row = N_NODES - 1;
            const float* ap = x + (size_t)row * 256 + kt + kg * 8;
            float4 lo = *(const float4*)ap;
            float4 hi = *(const float4*)(ap + 4);
            h8v t;
            t[0] = (_Float16)lo.x; t[1] = (_Float16)lo.y;
            t[2] = (_Float16)lo.z; t[3] = (_Float16)lo.w;
            t[4] = (_Float16)hi.x; t[5] = (_Float16)hi.y;
            t[6] = (_Float16)hi.z; t[7] = (_Float16)hi.w;
            a[rf] = t;
        }
        #pragma unroll
        for (int cf = 0; cf < 8; ++cf) {
            h8v b = *(const h8v*)(W1T + (size_t)(cf * 16 + r0) * 256 + kt + kg * 8);
            acc[0][cf] = __builtin_amdgcn_mfma_f32_16x16x32_f16(a[0], b, acc[0][cf], 0, 0, 0);
            acc[1][cf] = __builtin_amdgcn_mfma_f32_16x16x32_f16(a[1], b, acc[1][cf], 0, 0, 0);
        }
    }
    // C/D: col = lane&15, row = (lane>>4)*4 + reg
    #pragma unroll
    for (int rf = 0; rf < 2; ++rf) {
        #pragma unroll
        for (int r = 0; r < 4; ++r) {
            int row = rowbase + rf * 16 + kg * 4 + r;
            if (row < N_NODES) {
                _Float16* orow = h1h + (size_t)row * 128 + r0;
                #pragma unroll
                for (int cf = 0; cf < 8; ++cf)
                    orow[cf * 16] = (_Float16)acc[rf][cf][r];
            }
        }
    }
}

// ------- per-node attention logits, layer 1 (reads fp16 h1) -------

__global__ void k_logits1(const __half* __restrict__ h1h,
                          const float* __restrict__ a1s, const float* __restrict__ a1d,
                          float* __restrict__ s1s, float* __restrict__ s1d) {
    int idx = blockIdx.x * blockDim.x + threadIdx.x;   // N*8
    if (idx >= N_NODES * 8) return;
    int n = idx >> 3, h = idx & 7;
    const __half2* hp2 = (const __half2*)(h1h + (size_t)n * 128 + h * 16);
    float ss = 0.f, sd = 0.f;
    #pragma unroll
    for (int c2 = 0; c2 < 8; ++c2) {
        float2 v = __half22float2(hp2[c2]);
        ss += v.x * a1s[h * 16 + 2 * c2] + v.y * a1s[h * 16 + 2 * c2 + 1];
        sd += v.x * a1d[h * 16 + 2 * c2] + v.y * a1d[h * 16 + 2 * c2 + 1];
    }
    s1s[idx] = ss;
    s1d[idx] = sd;
}

// ------- layer-1 aggregate + bias + ELU (wave per node, single fused pass) -------

__global__ __launch_bounds__(256) void k_agg1(const __half* __restrict__ h1h,
        const float* __restrict__ s1s, const float* __restrict__ s1d,
        const int* __restrict__ offs, const unsigned short* __restrict__ csr_src,
        const float* __restrict__ b1, float* __restrict__ h2o) {
    int wave = threadIdx.x >> 6;
    int lane = threadIdx.x & 63;
    int n = blockIdx.x * 4 + wave;   // N = 4*12500 exactly
    int beg = offs[n];
    int deg = offs[n + 1] - beg;     // >= 1 (self-loop)

    int h = lane & 7;        // head this lane evaluates exp for
    int slot = lane >> 3;    // edge slot within 8-chunk
    int hd = lane >> 3;      // head of this lane's channel pair
    float sdh = s1d[n * 8 + h];

    float dsum = 0.f;
    float accx = 0.f, accy = 0.f;
    for (int chunk = 0; chunk < deg; chunk += 8) {
        int i = chunk + slot;
        int esrc = csr_src[beg + ((i < deg) ? i : (deg - 1))];   // clamped, valid
        float aN = 0.f;
        if (i < deg) {
            float e = s1s[esrc * 8 + h] + sdh;
            e = (e > 0.f) ? e : 0.2f * e;
            aN = __expf(e);          // no max subtraction needed
            dsum += aN;
        }
        int   srcs[8];
        float as[8];
        #pragma unroll
        for (int s = 0; s < 8; ++s) {
            srcs[s] = __shfl(esrc, s * 8);
            as[s]   = __shfl(aN, s * 8 + hd);   // 0 for inactive slots
        }
        __half2 v[8];
        #pragma unroll
        for (int s = 0; s < 8; ++s)
            v[s] = *(const __half2*)(h1h + (size_t)srcs[s] * 128 + 2 * lane);
        #pragma unroll
        for (int s = 0; s < 8; ++s) {
            float2 vf = __half22float2(v[s]);
            accx += as[s] * vf.x;
            accy += as[s] * vf.y;
        }
    }
    dsum += __shfl_xor(dsum, 8);
    dsum += __shfl_xor(dsum, 16);
    dsum += __shfl_xor(dsum, 32);
    float rd = 1.f / __shfl(dsum, hd);

    float v0 = accx * rd + b1[2 * lane];
    v0 = (v0 > 0.f) ? v0 : (__expf(v0) - 1.f);
    float v1 = accy * rd + b1[2 * lane + 1];
    v1 = (v1 > 0.f) ? v1 : (__expf(v1) - 1.f);
    *(float2*)(h2o + (size_t)n * 128 + 2 * lane) = make_float2(v0, v1);
}

// ------- GEMM2: g2h(fp16) = h2 @ W2  (thread = node, 48 accs) + logits -------

__global__ __launch_bounds__(256) void k_gemm2(const float* __restrict__ h2,
        const float* __restrict__ W2p,
        const float* __restrict__ a2s, const float* __restrict__ a2d,
        __half* __restrict__ g2h, float* __restrict__ s2s, float* __restrict__ s2d) {
    int n = blockIdx.x * 256 + threadIdx.x;
    bool valid = (n < N_NODES);
    int nn = valid ? n : (N_NODES - 1);
    const float* hrow = h2 + (size_t)nn * 128;
    float4 acc[12];
    #pragma unroll
    for (int j = 0; j < 12; ++j) acc[j] = make_float4(0.f, 0.f, 0.f, 0.f);
    #pragma unroll 1
    for (int k = 0; k < 128; k += 4) {
        float4 hv = *(const float4*)(hrow + k);
        float hk[4] = {hv.x, hv.y, hv.z, hv.w};
        #pragma unroll
        for (int kk = 0; kk < 4; ++kk) {
            const float* wrow = W2p + (size_t)(k + kk) * 48;
            #pragma unroll
            for (int j = 0; j < 12; ++j) {
                float4 wv = *(const float4*)(wrow + j * 4);
                acc[j].x += hk[kk] * wv.x;
                acc[j].y += hk[kk] * wv.y;
                acc[j].z += hk[kk] * wv.z;
                acc[j].w += hk[kk] * wv.w;
            }
        }
    }
    float vs = 0.f, vd = 0.f;
    #pragma unroll
    for (int j = 0; j < 12; ++j) {
        int c = j * 4;
        vs += acc[j].x * a2s[c + 0]; vd += acc[j].x * a2d[c + 0];
        vs += acc[j].y * a2s[c + 1]; vd += acc[j].y * a2d[c + 1];
        vs += acc[j].z * a2s[c + 2]; vd += acc[j].z * a2d[c + 2];
        if (j < 11) { vs += acc[j].w * a2s[c + 3]; vd += acc[j].w * a2d[c + 3]; }
    }
    if (valid) {
        __half2* orow = (__half2*)(g2h + (size_t)n * 48);
        #pragma unroll
        for (int j = 0; j < 12; ++j) {
            orow[j * 2 + 0] = __floats2half2_rn(acc[j].x, acc[j].y);
            orow[j * 2 + 1] = __floats2half2_rn(acc[j].z, acc[j].w);
        }
        s2s[n] = vs;
        s2d[n] = vd;
    }
}

// ------- layer-2 aggregate + bias + log_softmax (single fused pass) -------

__global__ __launch_bounds__(256) void k_agg2(const __half* __restrict__ g2h,
        const float* __restrict__ s2s, const float* __restrict__ s2d,
        const int* __restrict__ offs, const unsigned short* __restrict__ csr_src,
        const float* __restrict__ b2, float* __restrict__ outp) {
    int wave = threadIdx.x >> 6, lane = threadIdx.x & 63;
    int n = blockIdx.x * 4 + wave;
    int beg = offs[n];
    int deg = offs[n + 1] - beg;
    float sdn = s2d[n];
    int c = (lane < 47) ? lane : 47;   // col 47 is zero padding, valid address

    float dsum = 0.f;
    float acc = 0.f;
    for (int chunk = 0; chunk < deg; chunk += 64) {
        int i = chunk + lane;
        int esrc = csr_src[beg + ((i < deg) ? i : (deg - 1))];
        float aN = 0.f;
        if (i < deg) {
            float e = s2s[esrc] + sdn;
            e = (e > 0.f) ? e : 0.2f * e;
            aN = __expf(e);
            dsum += aN;
        }
        int lim = deg - chunk; if (lim > 64) lim = 64;
        for (int g = 0; g < lim; g += 8) {
            int   srcs[8];
            float as[8];
            #pragma unroll
            for (int s = 0; s < 8; ++s) {
                srcs[s] = __shfl(esrc, g + s);
                as[s]   = __shfl(aN, g + s);     // 0 for inactive
            }
            __half v[8];
            #pragma unroll
            for (int s = 0; s < 8; ++s) v[s] = g2h[(size_t)srcs[s] * 48 + c];
            #pragma unroll
            for (int s = 0; s < 8; ++s) acc += as[s] * __half2float(v[s]);
        }
    }
    #pragma unroll
    for (int o = 32; o; o >>= 1) dsum += __shfl_xor(dsum, o);
    acc *= 1.f / dsum;

    float l = (lane < 47) ? acc + b2[lane] : -1e30f;
    float rm = l;
    #pragma unroll
    for (int o = 32; o; o >>= 1) rm = fmaxf(rm, __shfl_xor(rm, o));
    float p = (lane < 47) ? __expf(l - rm) : 0.f;
    float ps = p;
    #pragma unroll
    for (int o = 32; o; o >>= 1) ps += __shfl_xor(ps, o);
    float lse = rm + __logf(ps);
    if (lane < 47) outp[(size_t)n * 47 + lane] = l - lse;
}

// ---------------- launcher ----------------

extern "C" void kernel_launch(void* const* d_in, const int* in_sizes, int n_in,
                              void* d_out, int out_size, void* d_ws, size_t ws_size,
                              hipStream_t stream) {
    const float* x   = (const float*)d_in[0];
    const int*   ei  = (const int*)d_in[1];
    const float* W1  = (const float*)d_in[2];
    const float* a1s = (const float*)d_in[3];
    const float* a1d = (const float*)d_in[4];
    const float* b1  = (const float*)d_in[5];
    const float* W2  = (const float*)d_in[6];
    const float* a2s = (const float*)d_in[7];
    const float* a2d = (const float*)d_in[8];
    const float* b2  = (const float*)d_in[9];
    float* outp = (float*)d_out;

    char* ws = (char*)d_ws;
    size_t off = 0;
    auto alloc = [&](size_t bytes) -> void* {
        void* p = ws + off;
        off += (bytes + 255) & ~(size_t)255;
        return p;
    };
    int* gh      = (int*)alloc((size_t)NBLKC * NBUCK * 4);
    int* tot     = (int*)alloc((size_t)NBUCK * 4);
    int* boff    = (int*)alloc((size_t)(NBUCK + 1) * 4);
    unsigned int* brec = (unsigned int*)alloc((size_t)E2 * 4);
    unsigned short* csr_src = (unsigned short*)alloc((size_t)E2 * 2);
    int* offs    = (int*)alloc((size_t)(N_NODES + 1) * 4);
    __half* h1h  = (__half*)alloc((size_t)N_NODES * 128 * 2);
    float* s1s   = (float*)alloc((size_t)N_NODES * 8 * 4);
    float* s1d   = (float*)alloc((size_t)N_NODES * 8 * 4);
    float* h2    = (float*)alloc((size_t)N_NODES * 128 * 4);
    __half* g2h  = (__half*)alloc((size_t)N_NODES * 48 * 2);
    float* s2s   = (float*)alloc((size_t)N_NODES * 4);
    float* s2d   = (float*)alloc((size_t)N_NODES * 4);
    float* W2p   = (float*)alloc((size_t)128 * 48 * 4);
    _Float16* W1T = (_Float16*)alloc((size_t)128 * 256 * 2);

    (void)in_sizes; (void)n_in; (void)out_size; (void)ws_size;

    // CSR build: counting sort
    k_prepw1<<<128, 256, 0, stream>>>(W1, W1T);
    k_hist<<<NBLKC, 256, 0, stream>>>(ei, gh);
    k_colscan<<<(NBUCK + 3) / 4, 256, 0, stream>>>(gh, tot);
    k_btot<<<1, 1024, 0, stream>>>(tot, boff, W2, W2p);
    k_place<<<NBLKC, 256, 0, stream>>>(ei, gh, boff, brec);
    k_finalize<<<NBUCK, 256, 0, stream>>>(brec, boff, csr_src, offs);

    // layer 1
    k_gemm1<<<(N_NODES + 63) / 64, 128, 0, stream>>>(x, W1T, (_Float16*)h1h);
    k_logits1<<<(N_NODES * 8 + 255) / 256, 256, 0, stream>>>(h1h, a1s, a1d, s1s, s1d);
    k_agg1<<<N_NODES / 4, 256, 0, stream>>>(h1h, s1s, s1d, offs, csr_src, b1, h2);

    // layer 2
    k_gemm2<<<(N_NODES + 255) / 256, 256, 0, stream>>>(h2, W2p, a2s, a2d, g2h, s2s, s2d);
    k_agg2<<<N_NODES / 4, 256, 0, stream>>>(g2h, s2s, s2d, offs, csr_src, b2, outp);
}

// Round 13
// 179.944 us; speedup vs baseline: 1.2395x; 1.0084x over previous
//
#include <hip/hip_runtime.h>
#include <hip/hip_fp16.h>

#define N_NODES 50000
#define N_EDGES 800000
#define E2 (N_EDGES + N_NODES)   // 850000 edges incl self-loops

#define BSHIFT 6
#define BMASK 63
#define NBUCK 782            // ceil(50000/64) buckets of 64 dst each
#define EPB 4096             // edges per block in counting sort
#define NBLKC 208            // ceil(E2/EPB)

typedef _Float16 h8v __attribute__((ext_vector_type(8)));
typedef float f4v __attribute__((ext_vector_type(4)));

// ---------------- CSR build: counting sort (no global atomics) ----------------

// phase A: per-block LDS histogram -> gh[blk][b]
__global__ __launch_bounds__(256) void k_hist(const int* __restrict__ ei,
                                              int* __restrict__ gh) {
    __shared__ int h[NBUCK];
    int tid = threadIdx.x;
    for (int b = tid; b < NBUCK; b += 256) h[b] = 0;
    __syncthreads();
    int base = blockIdx.x * EPB;
    for (int i = tid; i < EPB; i += 256) {
        int e = base + i;
        if (e < E2) {
            int dst = (e < N_EDGES) ? ei[N_EDGES + e] : (e - N_EDGES);
            atomicAdd(&h[dst >> BSHIFT], 1);
        }
    }
    __syncthreads();
    for (int b = tid; b < NBUCK; b += 256) gh[blockIdx.x * NBUCK + b] = h[b];
}

// phase B1: per-bucket exclusive scan across blocks (wave per bucket)
__global__ __launch_bounds__(256) void k_colscan(int* __restrict__ gh,
                                                 int* __restrict__ tot) {
    int wave = threadIdx.x >> 6, lane = threadIdx.x & 63;
    int b = blockIdx.x * 4 + wave;
    if (b >= NBUCK) return;
    int carry = 0;
    for (int c = 0; c < NBLKC; c += 64) {
        int k = c + lane;
        int v = (k < NBLKC) ? gh[k * NBUCK + b] : 0;
        int x = v;
        #pragma unroll
        for (int o = 1; o < 64; o <<= 1) { int y = __shfl_up(x, o); if (lane >= o) x += y; }
        if (k < NBLKC) gh[k * NBUCK + b] = carry + x - v;   // exclusive
        carry += __shfl(x, 63);
    }
    if (lane == 0) tot[b] = carry;
}

// phase B2 (1 block): scan bucket totals -> boff; + W2 pad
__global__ __launch_bounds__(1024) void k_btot(const int* __restrict__ tot,
        int* __restrict__ boff, const float* __restrict__ W2, float* __restrict__ W2p) {
    int t = threadIdx.x;
    for (int i = t; i < 128 * 48; i += 1024) {
        int k = i / 48, c = i - k * 48;
        W2p[i] = (c < 47) ? W2[k * 47 + c] : 0.f;
    }
    int v = (t < NBUCK) ? tot[t] : 0;
    __shared__ int ws[16];
    int lane = t & 63, w = t >> 6;
    int x = v;
    #pragma unroll
    for (int o = 1; o < 64; o <<= 1) { int y = __shfl_up(x, o); if (lane >= o) x += y; }
    if (lane == 63) ws[w] = x;
    __syncthreads();
    if (t == 0) {
        #pragma unroll
        for (int j = 1; j < 16; ++j) ws[j] += ws[j - 1];
    }
    __syncthreads();
    int add = (w == 0) ? 0 : ws[w - 1];
    int excl = add + x - v;
    if (t < NBUCK) boff[t] = excl;
    if (t == NBUCK - 1) boff[NBUCK] = excl + v;
}

// phase C: deterministic placement (LDS ranks only)
__global__ __launch_bounds__(256) void k_place(const int* __restrict__ ei,
        const int* __restrict__ gh, const int* __restrict__ boff,
        unsigned int* __restrict__ brec) {
    __shared__ int sbase[NBUCK];
    __shared__ int cnt[NBUCK];
    int tid = threadIdx.x;
    for (int b = tid; b < NBUCK; b += 256) {
        sbase[b] = boff[b] + gh[blockIdx.x * NBUCK + b];
        cnt[b] = 0;
    }
    __syncthreads();
    int base = blockIdx.x * EPB;
    for (int i = tid; i < EPB; i += 256) {
        int e = base + i;
        if (e < E2) {
            int src, dst;
            if (e < N_EDGES) { src = ei[e]; dst = ei[N_EDGES + e]; }
            else             { src = dst = e - N_EDGES; }
            int b = dst >> BSHIFT;
            int r = atomicAdd(&cnt[b], 1);
            brec[sbase[b] + r] = ((unsigned int)(dst & BMASK) << 16) | (unsigned int)src;
        }
    }
}

// per-bucket finalize: LDS histogram/scan/scatter -> coalesced csr write + offs
__global__ __launch_bounds__(256) void k_finalize(const unsigned int* __restrict__ brec,
        const int* __restrict__ boff, unsigned short* __restrict__ csr_src,
        int* __restrict__ offs) {
    int B = blockIdx.x;
    int tid = threadIdx.x;
    int base = boff[B];
    int total = boff[B + 1] - base;
    __shared__ int hist[64], cur[64];
    __shared__ unsigned short stage[2048];
    if (tid < 64) hist[tid] = 0;
    __syncthreads();
    const unsigned int* bp = brec + base;
    for (int i = tid; i < total; i += 256) atomicAdd(&hist[bp[i] >> 16], 1);
    __syncthreads();
    if (tid < 64) {   // wave 0: exclusive scan over 64 node-counts
        int v = hist[tid];
        int x = v;
        #pragma unroll
        for (int o = 1; o < 64; o <<= 1) { int y = __shfl_up(x, o); if (tid >= o) x += y; }
        int excl = x - v;
        cur[tid] = excl;
        int n = B * 64 + tid;
        if (n < N_NODES) offs[n] = base + excl;
    }
    if (B == NBUCK - 1 && tid == 0) offs[N_NODES] = boff[NBUCK];
    __syncthreads();
    if (total <= 2048) {
        for (int i = tid; i < total; i += 256) {
            unsigned int r = bp[i];
            int p = atomicAdd(&cur[r >> 16], 1);
            stage[p] = (unsigned short)(r & 0xFFFFu);
        }
        __syncthreads();
        for (int i = tid; i < total; i += 256) csr_src[base + i] = stage[i];
    } else {   // safety fallback (never hit for this graph)
        for (int i = tid; i < total; i += 256) {
            unsigned int r = bp[i];
            int p = atomicAdd(&cur[r >> 16], 1);
            csr_src[base + p] = (unsigned short)(r & 0xFFFFu);
        }
    }
}

// ------- W1 transpose+fp16: W1T[c][k] = W1[k][c] -------

__global__ void k_prepw1(const float* __restrict__ W1, _Float16* __restrict__ W1T) {
    int i = blockIdx.x * 256 + threadIdx.x;   // 128*256
    if (i >= 128 * 256) return;
    int c = i >> 8, k = i & 255;
    W1T[i] = (_Float16)W1[k * 128 + c];
}

// ------- GEMM1 (MFMA): h1h = fp16(x @ W1), no LDS -------

__global__ __launch_bounds__(128) void k_gemm1(const float* __restrict__ x,
        const _Float16* __restrict__ W1T, _Float16* __restrict__ h1h) {
    int lane = threadIdx.x & 63;
    int wv = threadIdx.x >> 6;            // 0..1
    int rowbase = blockIdx.x * 64 + wv * 32;
    int r0 = lane & 15;
    int kg = lane >> 4;                   // 0..3
    f4v acc[2][8];
    #pragma unroll
    for (int i = 0; i < 2; ++i)
        #pragma unroll
        for (int j = 0; j < 8; ++j) acc[i][j] = (f4v)0.f;

    #pragma unroll 1
    for (int kt = 0; kt < 256; kt += 32) {
        h8v a[2];
        #pragma unroll
        for (int rf = 0; rf < 2; ++rf) {
            int row = rowbase + rf * 16 + r0;
            if (row >= N_NODES) row = N_NODES - 1;
            const float* ap = x + (size_t)row * 256 + kt + kg * 8;
            float4 lo = *(const float4*)ap;
            float4 hi = *(const float4*)(ap + 4);
            h8v t;
            t[0] = (_Float16)lo.x; t[1] = (_Float16)lo.y;
            t[2] = (_Float16)lo.z; t[3] = (_Float16)lo.w;
            t[4] = (_Float16)hi.x; t[5] = (_Float16)hi.y;
            t[6] = (_Float16)hi.z; t[7] = (_Float16)hi.w;
            a[rf] = t;
        }
        #pragma unroll
        for (int cf = 0; cf < 8; ++cf) {
            h8v b = *(const h8v*)(W1T + (size_t)(cf * 16 + r0) * 256 + kt + kg * 8);
            acc[0][cf] = __builtin_amdgcn_mfma_f32_16x16x32_f16(a[0], b, acc[0][cf], 0, 0, 0);
            acc[1][cf] = __builtin_amdgcn_mfma_f32_16x16x32_f16(a[1], b, acc[1][cf], 0, 0, 0);
        }
    }
    // C/D: col = lane&15, row = (lane>>4)*4 + reg
    #pragma unroll
    for (int rf = 0; rf < 2; ++rf) {
        #pragma unroll
        for (int r = 0; r < 4; ++r) {
            int row = rowbase + rf * 16 + kg * 4 + r;
            if (row < N_NODES) {
                _Float16* orow = h1h + (size_t)row * 128 + r0;
                #pragma unroll
                for (int cf = 0; cf < 8; ++cf)
                    orow[cf * 16] = (_Float16)acc[rf][cf][r];
            }
        }
    }
}

// ------- per-node attention logits, layer 1 (reads fp16 h1) -------

__global__ void k_logits1(const __half* __restrict__ h1h,
                          const float* __restrict__ a1s, const float* __restrict__ a1d,
                          float* __restrict__ s1s, float* __restrict__ s1d) {
    int idx = blockIdx.x * blockDim.x + threadIdx.x;   // N*8
    if (idx >= N_NODES * 8) return;
    int n = idx >> 3, h = idx & 7;
    const __half2* hp2 = (const __half2*)(h1h + (size_t)n * 128 + h * 16);
    float ss = 0.f, sd = 0.f;
    #pragma unroll
    for (int c2 = 0; c2 < 8; ++c2) {
        float2 v = __half22float2(hp2[c2]);
        ss += v.x * a1s[h * 16 + 2 * c2] + v.y * a1s[h * 16 + 2 * c2 + 1];
        sd += v.x * a1d[h * 16 + 2 * c2] + v.y * a1d[h * 16 + 2 * c2 + 1];
    }
    s1s[idx] = ss;
    s1d[idx] = sd;
}

// ------- layer-1 aggregate + bias + ELU (wave per node) -------
// Gather restructured: 4 groups of 16 lanes; each group reads one edge's full
// 256B row as dwordx4 (16B/lane). acc[8] channels per lane; fold groups at end.

__global__ __launch_bounds__(256) void k_agg1(const __half* __restrict__ h1h,
        const float* __restrict__ s1s, const float* __restrict__ s1d,
        const int* __restrict__ offs, const unsigned short* __restrict__ csr_src,
        const float* __restrict__ b1, float* __restrict__ h2o) {
    int wave = threadIdx.x >> 6;
    int lane = threadIdx.x & 63;
    int n = blockIdx.x * 4 + wave;   // N = 4*12500 exactly
    int beg = offs[n];
    int deg = offs[n + 1] - beg;     // >= 1 (self-loop)

    int h = lane & 7;        // head this lane evaluates exp for
    int slot = lane >> 3;    // edge slot within 8-chunk (exp phase)
    int grp = lane >> 4;     // gather group 0..3
    int cidx = lane & 15;    // 16B channel block within row
    int hc = cidx >> 1;      // head of this lane's 8 channels
    float sdh = s1d[n * 8 + h];

    float dsum = 0.f;
    float acc[8] = {0.f, 0.f, 0.f, 0.f, 0.f, 0.f, 0.f, 0.f};
    for (int chunk = 0; chunk < deg; chunk += 8) {
        int i = chunk + slot;
        int esrc = csr_src[beg + ((i < deg) ? i : (deg - 1))];   // clamped, valid
        float aN = 0.f;
        if (i < deg) {
            float e = s1s[esrc * 8 + h] + sdh;
            e = (e > 0.f) ? e : 0.2f * e;
            aN = __expf(e);          // no max subtraction needed
            dsum += aN;
        }
        // 2 gather steps x 4 edges; each 16-lane group reads one row (dwordx4/lane)
        int   src0 = __shfl(esrc, (grp) * 8);
        float a0   = __shfl(aN, (grp) * 8 + hc);
        int   src1 = __shfl(esrc, (4 + grp) * 8);
        float a1   = __shfl(aN, (4 + grp) * 8 + hc);
        h8v v0 = *(const h8v*)(h1h + (size_t)src0 * 128 + cidx * 8);
        h8v v1 = *(const h8v*)(h1h + (size_t)src1 * 128 + cidx * 8);
        #pragma unroll
        for (int j = 0; j < 8; ++j) acc[j] += a0 * (float)v0[j];
        #pragma unroll
        for (int j = 0; j < 8; ++j) acc[j] += a1 * (float)v1[j];
    }
    // denom: fold over slots; lane l holds head (l&7) total
    dsum += __shfl_xor(dsum, 8);
    dsum += __shfl_xor(dsum, 16);
    dsum += __shfl_xor(dsum, 32);
    float rd = 1.f / __shfl(dsum, hc);   // lane hc has h == hc
    // fold acc across the 4 gather groups (channels align across lane±16/32)
    #pragma unroll
    for (int j = 0; j < 8; ++j) {
        acc[j] += __shfl_xor(acc[j], 16);
        acc[j] += __shfl_xor(acc[j], 32);
    }
    // each group writes its 2-channel slice -> fully coalesced 512B/node
    int c0 = cidx * 8 + grp * 2;
    float va = acc[grp * 2] * rd + b1[c0];
    va = (va > 0.f) ? va : (__expf(va) - 1.f);
    float vb = acc[grp * 2 + 1] * rd + b1[c0 + 1];
    vb = (vb > 0.f) ? vb : (__expf(vb) - 1.f);
    *(float2*)(h2o + (size_t)n * 128 + c0) = make_float2(va, vb);
}

// ------- GEMM2: g2h(fp16) = h2 @ W2  (thread = node, 48 accs) + logits -------

__global__ __launch_bounds__(256) void k_gemm2(const float* __restrict__ h2,
        const float* __restrict__ W2p,
        const float* __restrict__ a2s, const float* __restrict__ a2d,
        __half* __restrict__ g2h, float* __restrict__ s2s, float* __restrict__ s2d) {
    int n = blockIdx.x * 256 + threadIdx.x;
    bool valid = (n < N_NODES);
    int nn = valid ? n : (N_NODES - 1);
    const float* hrow = h2 + (size_t)nn * 128;
    float4 acc[12];
    #pragma unroll
    for (int j = 0; j < 12; ++j) acc[j] = make_float4(0.f, 0.f, 0.f, 0.f);
    #pragma unroll 1
    for (int k = 0; k < 128; k += 4) {
        float4 hv = *(const float4*)(hrow + k);
        float hk[4] = {hv.x, hv.y, hv.z, hv.w};
        #pragma unroll
        for (int kk = 0; kk < 4; ++kk) {
            const float* wrow = W2p + (size_t)(k + kk) * 48;
            #pragma unroll
            for (int j = 0; j < 12; ++j) {
                float4 wv = *(const float4*)(wrow + j * 4);
                acc[j].x += hk[kk] * wv.x;
                acc[j].y += hk[kk] * wv.y;
                acc[j].z += hk[kk] * wv.z;
                acc[j].w += hk[kk] * wv.w;
            }
        }
    }
    float vs = 0.f, vd = 0.f;
    #pragma unroll
    for (int j = 0; j < 12; ++j) {
        int c = j * 4;
        vs += acc[j].x * a2s[c + 0]; vd += acc[j].x * a2d[c + 0];
        vs += acc[j].y * a2s[c + 1]; vd += acc[j].y * a2d[c + 1];
        vs += acc[j].z * a2s[c + 2]; vd += acc[j].z * a2d[c + 2];
        if (j < 11) { vs += acc[j].w * a2s[c + 3]; vd += acc[j].w * a2d[c + 3]; }
    }
    if (valid) {
        __half2* orow = (__half2*)(g2h + (size_t)n * 48);
        #pragma unroll
        for (int j = 0; j < 12; ++j) {
            orow[j * 2 + 0] = __floats2half2_rn(acc[j].x, acc[j].y);
            orow[j * 2 + 1] = __floats2half2_rn(acc[j].z, acc[j].w);
        }
        s2s[n] = vs;
        s2d[n] = vd;
    }
}

// ------- layer-2 aggregate + bias + log_softmax (single fused pass) -------

__global__ __launch_bounds__(256) void k_agg2(const __half* __restrict__ g2h,
        const float* __restrict__ s2s, const float* __restrict__ s2d,
        const int* __restrict__ offs, const unsigned short* __restrict__ csr_src,
        const float* __restrict__ b2, float* __restrict__ outp) {
    int wave = threadIdx.x >> 6, lane = threadIdx.x & 63;
    int n = blockIdx.x * 4 + wave;
    int beg = offs[n];
    int deg = offs[n + 1] - beg;
    float sdn = s2d[n];
    int c = (lane < 47) ? lane : 47;   // col 47 is zero padding, valid address

    float dsum = 0.f;
    float acc = 0.f;
    for (int chunk = 0; chunk < deg; chunk += 64) {
        int i = chunk + lane;
        int esrc = csr_src[beg + ((i < deg) ? i : (deg - 1))];
        float aN = 0.f;
        if (i < deg) {
            float e = s2s[esrc] + sdn;
            e = (e > 0.f) ? e : 0.2f * e;
            aN = __expf(e);
            dsum += aN;
        }
        int lim = deg - chunk; if (lim > 64) lim = 64;
        for (int g = 0; g < lim; g += 8) {
            int   srcs[8];
            float as[8];
            #pragma unroll
            for (int s = 0; s < 8; ++s) {
                srcs[s] = __shfl(esrc, g + s);
                as[s]   = __shfl(aN, g + s);     // 0 for inactive
            }
            __half v[8];
            #pragma unroll
            for (int s = 0; s < 8; ++s) v[s] = g2h[(size_t)srcs[s] * 48 + c];
            #pragma unroll
            for (int s = 0; s < 8; ++s) acc += as[s] * __half2float(v[s]);
        }
    }
    #pragma unroll
    for (int o = 32; o; o >>= 1) dsum += __shfl_xor(dsum, o);
    acc *= 1.f / dsum;

    float l = (lane < 47) ? acc + b2[lane] : -1e30f;
    float rm = l;
    #pragma unroll
    for (int o = 32; o; o >>= 1) rm = fmaxf(rm, __shfl_xor(rm, o));
    float p = (lane < 47) ? __expf(l - rm) : 0.f;
    float ps = p;
    #pragma unroll
    for (int o = 32; o; o >>= 1) ps += __shfl_xor(ps, o);
    float lse = rm + __logf(ps);
    if (lane < 47) outp[(size_t)n * 47 + lane] = l - lse;
}

// ---------------- launcher ----------------

extern "C" void kernel_launch(void* const* d_in, const int* in_sizes, int n_in,
                              void* d_out, int out_size, void* d_ws, size_t ws_size,
                              hipStream_t stream) {
    const float* x   = (const float*)d_in[0];
    const int*   ei  = (const int*)d_in[1];
    const float* W1  = (const float*)d_in[2];
    const float* a1s = (const float*)d_in[3];
    const float* a1d = (const float*)d_in[4];
    const float* b1  = (const float*)d_in[5];
    const float* W2  = (const float*)d_in[6];
    const float* a2s = (const float*)d_in[7];
    const float* a2d = (const float*)d_in[8];
    const float* b2  = (const float*)d_in[9];
    float* outp = (float*)d_out;

    char* ws = (char*)d_ws;
    size_t off = 0;
    auto alloc = [&](size_t bytes) -> void* {
        void* p = ws + off;
        off += (bytes + 255) & ~(size_t)255;
        return p;
    };
    int* gh      = (int*)alloc((size_t)NBLKC * NBUCK * 4);
    int* tot     = (int*)alloc((size_t)NBUCK * 4);
    int* boff    = (int*)alloc((size_t)(NBUCK + 1) * 4);
    unsigned int* brec = (unsigned int*)alloc((size_t)E2 * 4);
    unsigned short* csr_src = (unsigned short*)alloc((size_t)E2 * 2);
    int* offs    = (int*)alloc((size_t)(N_NODES + 1) * 4);
    __half* h1h  = (__half*)alloc((size_t)N_NODES * 128 * 2);
    float* s1s   = (float*)alloc((size_t)N_NODES * 8 * 4);
    float* s1d   = (float*)alloc((size_t)N_NODES * 8 * 4);
    float* h2    = (float*)alloc((size_t)N_NODES * 128 * 4);
    __half* g2h  = (__half*)alloc((size_t)N_NODES * 48 * 2);
    float* s2s   = (float*)alloc((size_t)N_NODES * 4);
    float* s2d   = (float*)alloc((size_t)N_NODES * 4);
    float* W2p   = (float*)alloc((size_t)128 * 48 * 4);
    _Float16* W1T = (_Float16*)alloc((size_t)128 * 256 * 2);

    (void)in_sizes; (void)n_in; (void)out_size; (void)ws_size;

    // CSR build: counting sort
    k_prepw1<<<128, 256, 0, stream>>>(W1, W1T);
    k_hist<<<NBLKC, 256, 0, stream>>>(ei, gh);
    k_colscan<<<(NBUCK + 3) / 4, 256, 0, stream>>>(gh, tot);
    k_btot<<<1, 1024, 0, stream>>>(tot, boff, W2, W2p);
    k_place<<<NBLKC, 256, 0, stream>>>(ei, gh, boff, brec);
    k_finalize<<<NBUCK, 256, 0, stream>>>(brec, boff, csr_src, offs);

    // layer 1
    k_gemm1<<<(N_NODES + 63) / 64, 128, 0, stream>>>(x, W1T, (_Float16*)h1h);
    k_logits1<<<(N_NODES * 8 + 255) / 256, 256, 0, stream>>>(h1h, a1s, a1d, s1s, s1d);
    k_agg1<<<N_NODES / 4, 256, 0, stream>>>(h1h, s1s, s1d, offs, csr_src, b1, h2);

    // layer 2
    k_gemm2<<<(N_NODES + 255) / 256, 256, 0, stream>>>(h2, W2p, a2s, a2d, g2h, s2s, s2d);
    k_agg2<<<N_NODES / 4, 256, 0, stream>>>(g2h, s2s, s2d, offs, csr_src, b2, outp);
}

// Round 14
// 178.239 us; speedup vs baseline: 1.2513x; 1.0096x over previous
//
#include <hip/hip_runtime.h>
#include <hip/hip_fp16.h>

#define N_NODES 50000
#define N_EDGES 800000
#define E2 (N_EDGES + N_NODES)   // 850000 edges incl self-loops

#define BSHIFT 6
#define BMASK 63
#define NBUCK 782            // ceil(50000/64) buckets of 64 dst each
#define EPB 4096             // edges per block in counting sort
#define NBLKC 208            // ceil(E2/EPB)

typedef _Float16 h8v __attribute__((ext_vector_type(8)));
typedef float f4v __attribute__((ext_vector_type(4)));

// ---------------- CSR build: counting sort (no global atomics) ----------------

// phase A: per-block LDS histogram -> gh[blk][b]; block NBLKC preps W1T
__global__ __launch_bounds__(256) void k_hist(const int* __restrict__ ei,
        int* __restrict__ gh, const float* __restrict__ W1, _Float16* __restrict__ W1T) {
    if (blockIdx.x == NBLKC) {   // W1 transpose+fp16: W1T[c][k] = W1[k][c]
        for (int i = threadIdx.x; i < 128 * 256; i += 256) {
            int c = i >> 8, k = i & 255;
            W1T[i] = (_Float16)W1[k * 128 + c];
        }
        return;
    }
    __shared__ int h[NBUCK];
    int tid = threadIdx.x;
    for (int b = tid; b < NBUCK; b += 256) h[b] = 0;
    __syncthreads();
    int base = blockIdx.x * EPB;
    for (int i = tid; i < EPB; i += 256) {
        int e = base + i;
        if (e < E2) {
            int dst = (e < N_EDGES) ? ei[N_EDGES + e] : (e - N_EDGES);
            atomicAdd(&h[dst >> BSHIFT], 1);
        }
    }
    __syncthreads();
    for (int b = tid; b < NBUCK; b += 256) gh[blockIdx.x * NBUCK + b] = h[b];
}

// phase B1: per-bucket exclusive scan across blocks (wave per bucket)
__global__ __launch_bounds__(256) void k_colscan(int* __restrict__ gh,
                                                 int* __restrict__ tot) {
    int wave = threadIdx.x >> 6, lane = threadIdx.x & 63;
    int b = blockIdx.x * 4 + wave;
    if (b >= NBUCK) return;
    int carry = 0;
    for (int c = 0; c < NBLKC; c += 64) {
        int k = c + lane;
        int v = (k < NBLKC) ? gh[k * NBUCK + b] : 0;
        int x = v;
        #pragma unroll
        for (int o = 1; o < 64; o <<= 1) { int y = __shfl_up(x, o); if (lane >= o) x += y; }
        if (k < NBLKC) gh[k * NBUCK + b] = carry + x - v;   // exclusive
        carry += __shfl(x, 63);
    }
    if (lane == 0) tot[b] = carry;
}

// phase B2 (1 block): scan bucket totals -> boff; + W2 pad
__global__ __launch_bounds__(1024) void k_btot(const int* __restrict__ tot,
        int* __restrict__ boff, const float* __restrict__ W2, float* __restrict__ W2p) {
    int t = threadIdx.x;
    for (int i = t; i < 128 * 48; i += 1024) {
        int k = i / 48, c = i - k * 48;
        W2p[i] = (c < 47) ? W2[k * 47 + c] : 0.f;
    }
    int v = (t < NBUCK) ? tot[t] : 0;
    __shared__ int ws[16];
    int lane = t & 63, w = t >> 6;
    int x = v;
    #pragma unroll
    for (int o = 1; o < 64; o <<= 1) { int y = __shfl_up(x, o); if (lane >= o) x += y; }
    if (lane == 63) ws[w] = x;
    __syncthreads();
    if (t == 0) {
        #pragma unroll
        for (int j = 1; j < 16; ++j) ws[j] += ws[j - 1];
    }
    __syncthreads();
    int add = (w == 0) ? 0 : ws[w - 1];
    int excl = add + x - v;
    if (t < NBUCK) boff[t] = excl;
    if (t == NBUCK - 1) boff[NBUCK] = excl + v;
}

// phase C: deterministic placement (LDS ranks only)
__global__ __launch_bounds__(256) void k_place(const int* __restrict__ ei,
        const int* __restrict__ gh, const int* __restrict__ boff,
        unsigned int* __restrict__ brec) {
    __shared__ int sbase[NBUCK];
    __shared__ int cnt[NBUCK];
    int tid = threadIdx.x;
    for (int b = tid; b < NBUCK; b += 256) {
        sbase[b] = boff[b] + gh[blockIdx.x * NBUCK + b];
        cnt[b] = 0;
    }
    __syncthreads();
    int base = blockIdx.x * EPB;
    for (int i = tid; i < EPB; i += 256) {
        int e = base + i;
        if (e < E2) {
            int src, dst;
            if (e < N_EDGES) { src = ei[e]; dst = ei[N_EDGES + e]; }
            else             { src = dst = e - N_EDGES; }
            int b = dst >> BSHIFT;
            int r = atomicAdd(&cnt[b], 1);
            brec[sbase[b] + r] = ((unsigned int)(dst & BMASK) << 16) | (unsigned int)src;
        }
    }
}

// per-bucket finalize: LDS histogram/scan/scatter -> coalesced csr write + offs
__global__ __launch_bounds__(256) void k_finalize(const unsigned int* __restrict__ brec,
        const int* __restrict__ boff, unsigned short* __restrict__ csr_src,
        int* __restrict__ offs) {
    int B = blockIdx.x;
    int tid = threadIdx.x;
    int base = boff[B];
    int total = boff[B + 1] - base;
    __shared__ int hist[64], cur[64];
    __shared__ unsigned short stage[2048];
    if (tid < 64) hist[tid] = 0;
    __syncthreads();
    const unsigned int* bp = brec + base;
    for (int i = tid; i < total; i += 256) atomicAdd(&hist[bp[i] >> 16], 1);
    __syncthreads();
    if (tid < 64) {   // wave 0: exclusive scan over 64 node-counts
        int v = hist[tid];
        int x = v;
        #pragma unroll
        for (int o = 1; o < 64; o <<= 1) { int y = __shfl_up(x, o); if (tid >= o) x += y; }
        int excl = x - v;
        cur[tid] = excl;
        int n = B * 64 + tid;
        if (n < N_NODES) offs[n] = base + excl;
    }
    if (B == NBUCK - 1 && tid == 0) offs[N_NODES] = boff[NBUCK];
    __syncthreads();
    if (total <= 2048) {
        for (int i = tid; i < total; i += 256) {
            unsigned int r = bp[i];
            int p = atomicAdd(&cur[r >> 16], 1);
            stage[p] = (unsigned short)(r & 0xFFFFu);
        }
        __syncthreads();
        for (int i = tid; i < total; i += 256) csr_src[base + i] = stage[i];
    } else {   // safety fallback (never hit for this graph)
        for (int i = tid; i < total; i += 256) {
            unsigned int r = bp[i];
            int p = atomicAdd(&cur[r >> 16], 1);
            csr_src[base + p] = (unsigned short)(r & 0xFFFFu);
        }
    }
}

// ------- GEMM1 (MFMA): h1h = fp16(x @ W1), no LDS -------

__global__ __launch_bounds__(128) void k_gemm1(const float* __restrict__ x,
        const _Float16* __restrict__ W1T, _Float16* __restrict__ h1h) {
    int lane = threadIdx.x & 63;
    int wv = threadIdx.x >> 6;            // 0..1
    int rowbase = blockIdx.x * 64 + wv * 32;
    int r0 = lane & 15;
    int kg = lane >> 4;                   // 0..3
    f4v acc[2][8];
    #pragma unroll
    for (int i = 0; i < 2; ++i)
        #pragma unroll
        for (int j = 0; j < 8; ++j) acc[i][j] = (f4v)0.f;

    #pragma unroll 1
    for (int kt = 0; kt < 256; kt += 32) {
        h8v a[2];
        #pragma unroll
        for (int rf = 0; rf < 2; ++rf) {
            int row = rowbase + rf * 16 + r0;
            if (row >= N_NODES) row = N_NODES - 1;
            const float* ap = x + (size_t)row * 256 + kt + kg * 8;
            float4 lo = *(const float4*)ap;
            float4 hi = *(const float4*)(ap + 4);
            h8v t;
            t[0] = (_Float16)lo.x; t[1] = (_Float16)lo.y;
            t[2] = (_Float16)lo.z; t[3] = (_Float16)lo.w;
            t[4] = (_Float16)hi.x; t[5] = (_Float16)hi.y;
            t[6] = (_Float16)hi.z; t[7] = (_Float16)hi.w;
            a[rf] = t;
        }
        #pragma unroll
        for (int cf = 0; cf < 8; ++cf) {
            h8v b = *(const h8v*)(W1T + (size_t)(cf * 16 + r0) * 256 + kt + kg * 8);
            acc[0][cf] = __builtin_amdgcn_mfma_f32_16x16x32_f16(a[0], b, acc[0][cf], 0, 0, 0);
            acc[1][cf] = __builtin_amdgcn_mfma_f32_16x16x32_f16(a[1], b, acc[1][cf], 0, 0, 0);
        }
    }
    // C/D: col = lane&15, row = (lane>>4)*4 + reg
    #pragma unroll
    for (int rf = 0; rf < 2; ++rf) {
        #pragma unroll
        for (int r = 0; r < 4; ++r) {
            int row = rowbase + rf * 16 + kg * 4 + r;
            if (row < N_NODES) {
                _Float16* orow = h1h + (size_t)row * 128 + r0;
                #pragma unroll
                for (int cf = 0; cf < 8; ++cf)
                    orow[cf * 16] = (_Float16)acc[rf][cf][r];
            }
        }
    }
}

// ------- per-node attention logits, layer 1 (reads fp16 h1) -------

__global__ void k_logits1(const __half* __restrict__ h1h,
                          const float* __restrict__ a1s, const float* __restrict__ a1d,
                          float* __restrict__ s1s, float* __restrict__ s1d) {
    int idx = blockIdx.x * blockDim.x + threadIdx.x;   // N*8
    if (idx >= N_NODES * 8) return;
    int n = idx >> 3, h = idx & 7;
    const __half2* hp2 = (const __half2*)(h1h + (size_t)n * 128 + h * 16);
    float ss = 0.f, sd = 0.f;
    #pragma unroll
    for (int c2 = 0; c2 < 8; ++c2) {
        float2 v = __half22float2(hp2[c2]);
        ss += v.x * a1s[h * 16 + 2 * c2] + v.y * a1s[h * 16 + 2 * c2 + 1];
        sd += v.x * a1d[h * 16 + 2 * c2] + v.y * a1d[h * 16 + 2 * c2 + 1];
    }
    s1s[idx] = ss;
    s1d[idx] = sd;
}

// ------- layer-1 aggregate + bias + ELU (wave per node) -------
// 16-edge chunks: 4 gather rows in flight per lane. fp16 h2 output.

__global__ __launch_bounds__(256) void k_agg1(const __half* __restrict__ h1h,
        const float* __restrict__ s1s, const float* __restrict__ s1d,
        const int* __restrict__ offs, const unsigned short* __restrict__ csr_src,
        const float* __restrict__ b1, __half* __restrict__ h2o) {
    int wave = threadIdx.x >> 6;
    int lane = threadIdx.x & 63;
    int n = blockIdx.x * 4 + wave;   // N = 4*12500 exactly
    int beg = offs[n];
    int deg = offs[n + 1] - beg;     // >= 1 (self-loop)

    int h = lane & 7;        // head this lane evaluates exp for
    int slot = lane >> 3;    // edge slot within 8-sub-chunk (exp phase)
    int grp = lane >> 4;     // gather group 0..3
    int cidx = lane & 15;    // 16B channel block within row
    int hc = cidx >> 1;      // head of this lane's 8 channels
    float sdh = s1d[n * 8 + h];

    float dsum = 0.f;
    float acc[8] = {0.f, 0.f, 0.f, 0.f, 0.f, 0.f, 0.f, 0.f};
    for (int chunk = 0; chunk < deg; chunk += 16) {
        int i0 = chunk + slot;
        int i1 = chunk + 8 + slot;
        int e0 = csr_src[beg + ((i0 < deg) ? i0 : (deg - 1))];
        int e1 = csr_src[beg + ((i1 < deg) ? i1 : (deg - 1))];
        float a0 = 0.f, a1 = 0.f;
        if (i0 < deg) {
            float e = s1s[e0 * 8 + h] + sdh;
            e = (e > 0.f) ? e : 0.2f * e;
            a0 = __expf(e);
            dsum += a0;
        }
        if (i1 < deg) {
            float e = s1s[e1 * 8 + h] + sdh;
            e = (e > 0.f) ? e : 0.2f * e;
            a1 = __expf(e);
            dsum += a1;
        }
        // 4 gather steps; each 16-lane group reads one row (16B/lane)
        int   s0 = __shfl(e0, grp * 8);       float w0 = __shfl(a0, grp * 8 + hc);
        int   s1 = __shfl(e0, (4 + grp) * 8); float w1 = __shfl(a0, (4 + grp) * 8 + hc);
        int   s2 = __shfl(e1, grp * 8);       float w2 = __shfl(a1, grp * 8 + hc);
        int   s3 = __shfl(e1, (4 + grp) * 8); float w3 = __shfl(a1, (4 + grp) * 8 + hc);
        h8v v0 = *(const h8v*)(h1h + (size_t)s0 * 128 + cidx * 8);
        h8v v1 = *(const h8v*)(h1h + (size_t)s1 * 128 + cidx * 8);
        h8v v2 = *(const h8v*)(h1h + (size_t)s2 * 128 + cidx * 8);
        h8v v3 = *(const h8v*)(h1h + (size_t)s3 * 128 + cidx * 8);
        #pragma unroll
        for (int j = 0; j < 8; ++j) acc[j] += w0 * (float)v0[j];
        #pragma unroll
        for (int j = 0; j < 8; ++j) acc[j] += w1 * (float)v1[j];
        #pragma unroll
        for (int j = 0; j < 8; ++j) acc[j] += w2 * (float)v2[j];
        #pragma unroll
        for (int j = 0; j < 8; ++j) acc[j] += w3 * (float)v3[j];
    }
    // denom: fold over slots; lane l holds head (l&7) total
    dsum += __shfl_xor(dsum, 8);
    dsum += __shfl_xor(dsum, 16);
    dsum += __shfl_xor(dsum, 32);
    float rd = 1.f / __shfl(dsum, hc);   // lane hc has h == hc
    // fold acc across the 4 gather groups
    #pragma unroll
    for (int j = 0; j < 8; ++j) {
        acc[j] += __shfl_xor(acc[j], 16);
        acc[j] += __shfl_xor(acc[j], 32);
    }
    // each group writes its 2-channel slice (fp16)
    int c0 = cidx * 8 + grp * 2;
    float va = acc[grp * 2] * rd + b1[c0];
    va = (va > 0.f) ? va : (__expf(va) - 1.f);
    float vb = acc[grp * 2 + 1] * rd + b1[c0 + 1];
    vb = (vb > 0.f) ? vb : (__expf(vb) - 1.f);
    *(__half2*)(h2o + (size_t)n * 128 + c0) = __floats2half2_rn(va, vb);
}

// ------- GEMM2: g2h(fp16) = h2(fp16) @ W2  (thread = node) + logits -------

__global__ __launch_bounds__(256) void k_gemm2(const __half* __restrict__ h2,
        const float* __restrict__ W2p,
        const float* __restrict__ a2s, const float* __restrict__ a2d,
        __half* __restrict__ g2h, float* __restrict__ s2s, float* __restrict__ s2d) {
    int n = blockIdx.x * 256 + threadIdx.x;
    bool valid = (n < N_NODES);
    int nn = valid ? n : (N_NODES - 1);
    const __half2* hrow = (const __half2*)(h2 + (size_t)nn * 128);
    float4 acc[12];
    #pragma unroll
    for (int j = 0; j < 12; ++j) acc[j] = make_float4(0.f, 0.f, 0.f, 0.f);
    #pragma unroll 1
    for (int k = 0; k < 128; k += 4) {
        float2 h01 = __half22float2(hrow[k / 2]);
        float2 h23 = __half22float2(hrow[k / 2 + 1]);
        float hk[4] = {h01.x, h01.y, h23.x, h23.y};
        #pragma unroll
        for (int kk = 0; kk < 4; ++kk) {
            const float* wrow = W2p + (size_t)(k + kk) * 48;
            #pragma unroll
            for (int j = 0; j < 12; ++j) {
                float4 wv = *(const float4*)(wrow + j * 4);
                acc[j].x += hk[kk] * wv.x;
                acc[j].y += hk[kk] * wv.y;
                acc[j].z += hk[kk] * wv.z;
                acc[j].w += hk[kk] * wv.w;
            }
        }
    }
    float vs = 0.f, vd = 0.f;
    #pragma unroll
    for (int j = 0; j < 12; ++j) {
        int c = j * 4;
        vs += acc[j].x * a2s[c + 0]; vd += acc[j].x * a2d[c + 0];
        vs += acc[j].y * a2s[c + 1]; vd += acc[j].y * a2d[c + 1];
        vs += acc[j].z * a2s[c + 2]; vd += acc[j].z * a2d[c + 2];
        if (j < 11) { vs += acc[j].w * a2s[c + 3]; vd += acc[j].w * a2d[c + 3]; }
    }
    if (valid) {
        __half2* orow = (__half2*)(g2h + (size_t)n * 48);
        #pragma unroll
        for (int j = 0; j < 12; ++j) {
            orow[j * 2 + 0] = __floats2half2_rn(acc[j].x, acc[j].y);
            orow[j * 2 + 1] = __floats2half2_rn(acc[j].z, acc[j].w);
        }
        s2s[n] = vs;
        s2d[n] = vd;
    }
}

// ------- layer-2 aggregate + bias + log_softmax (single fused pass) -------

__global__ __launch_bounds__(256) void k_agg2(const __half* __restrict__ g2h,
        const float* __restrict__ s2s, const float* __restrict__ s2d,
        const int* __restrict__ offs, const unsigned short* __restrict__ csr_src,
        const float* __restrict__ b2, float* __restrict__ outp) {
    int wave = threadIdx.x >> 6, lane = threadIdx.x & 63;
    int n = blockIdx.x * 4 + wave;
    int beg = offs[n];
    int deg = offs[n + 1] - beg;
    float sdn = s2d[n];
    int c = (lane < 47) ? lane : 47;   // col 47 is zero padding, valid address

    float dsum = 0.f;
    float acc = 0.f;
    for (int chunk = 0; chunk < deg; chunk += 64) {
        int i = chunk + lane;
        int esrc = csr_src[beg + ((i < deg) ? i : (deg - 1))];
        float aN = 0.f;
        if (i < deg) {
            float e = s2s[esrc] + sdn;
            e = (e > 0.f) ? e : 0.2f * e;
            aN = __expf(e);
            dsum += aN;
        }
        int lim = deg - chunk; if (lim > 64) lim = 64;
        for (int g = 0; g < lim; g += 8) {
            int   srcs[8];
            float as[8];
            #pragma unroll
            for (int s = 0; s < 8; ++s) {
                srcs[s] = __shfl(esrc, g + s);
                as[s]   = __shfl(aN, g + s);     // 0 for inactive
            }
            __half v[8];
            #pragma unroll
            for (int s = 0; s < 8; ++s) v[s] = g2h[(size_t)srcs[s] * 48 + c];
            #pragma unroll
            for (int s = 0; s < 8; ++s) acc += as[s] * __half2float(v[s]);
        }
    }
    #pragma unroll
    for (int o = 32; o; o >>= 1) dsum += __shfl_xor(dsum, o);
    acc *= 1.f / dsum;

    float l = (lane < 47) ? acc + b2[lane] : -1e30f;
    float rm = l;
    #pragma unroll
    for (int o = 32; o; o >>= 1) rm = fmaxf(rm, __shfl_xor(rm, o));
    float p = (lane < 47) ? __expf(l - rm) : 0.f;
    float ps = p;
    #pragma unroll
    for (int o = 32; o; o >>= 1) ps += __shfl_xor(ps, o);
    float lse = rm + __logf(ps);
    if (lane < 47) outp[(size_t)n * 47 + lane] = l - lse;
}

// ---------------- launcher ----------------

extern "C" void kernel_launch(void* const* d_in, const int* in_sizes, int n_in,
                              void* d_out, int out_size, void* d_ws, size_t ws_size,
                              hipStream_t stream) {
    const float* x   = (const float*)d_in[0];
    const int*   ei  = (const int*)d_in[1];
    const float* W1  = (const float*)d_in[2];
    const float* a1s = (const float*)d_in[3];
    const float* a1d = (const float*)d_in[4];
    const float* b1  = (const float*)d_in[5];
    const float* W2  = (const float*)d_in[6];
    const float* a2s = (const float*)d_in[7];
    const float* a2d = (const float*)d_in[8];
    const float* b2  = (const float*)d_in[9];
    float* outp = (float*)d_out;

    char* ws = (char*)d_ws;
    size_t off = 0;
    auto alloc = [&](size_t bytes) -> void* {
        void* p = ws + off;
        off += (bytes + 255) & ~(size_t)255;
        return p;
    };
    int* gh      = (int*)alloc((size_t)NBLKC * NBUCK * 4);
    int* tot     = (int*)alloc((size_t)NBUCK * 4);
    int* boff    = (int*)alloc((size_t)(NBUCK + 1) * 4);
    unsigned int* brec = (unsigned int*)alloc((size_t)E2 * 4);
    unsigned short* csr_src = (unsigned short*)alloc((size_t)E2 * 2);
    int* offs    = (int*)alloc((size_t)(N_NODES + 1) * 4);
    __half* h1h  = (__half*)alloc((size_t)N_NODES * 128 * 2);
    float* s1s   = (float*)alloc((size_t)N_NODES * 8 * 4);
    float* s1d   = (float*)alloc((size_t)N_NODES * 8 * 4);
    __half* h2h  = (__half*)alloc((size_t)N_NODES * 128 * 2);
    __half* g2h  = (__half*)alloc((size_t)N_NODES * 48 * 2);
    float* s2s   = (float*)alloc((size_t)N_NODES * 4);
    float* s2d   = (float*)alloc((size_t)N_NODES * 4);
    float* W2p   = (float*)alloc((size_t)128 * 48 * 4);
    _Float16* W1T = (_Float16*)alloc((size_t)128 * 256 * 2);

    (void)in_sizes; (void)n_in; (void)out_size; (void)ws_size;

    // CSR build: counting sort (+ W1T prep fused into hist)
    k_hist<<<NBLKC + 1, 256, 0, stream>>>(ei, gh, W1, W1T);
    k_colscan<<<(NBUCK + 3) / 4, 256, 0, stream>>>(gh, tot);
    k_btot<<<1, 1024, 0, stream>>>(tot, boff, W2, W2p);
    k_place<<<NBLKC, 256, 0, stream>>>(ei, gh, boff, brec);
    k_finalize<<<NBUCK, 256, 0, stream>>>(brec, boff, csr_src, offs);

    // layer 1
    k_gemm1<<<(N_NODES + 63) / 64, 128, 0, stream>>>(x, W1T, (_Float16*)h1h);
    k_logits1<<<(N_NODES * 8 + 255) / 256, 256, 0, stream>>>(h1h, a1s, a1d, s1s, s1d);
    k_agg1<<<N_NODES / 4, 256, 0, stream>>>(h1h, s1s, s1d, offs, csr_src, b1, h2h);

    // layer 2
    k_gemm2<<<(N_NODES + 255) / 256, 256, 0, stream>>>(h2h, W2p, a2s, a2d, g2h, s2s, s2d);
    k_agg2<<<N_NODES / 4, 256, 0, stream>>>(g2h, s2s, s2d, offs, csr_src, b2, outp);
}